// Round 3
// baseline (443.658 us; speedup 1.0000x reference)
//
#include <hip/hip_runtime.h>
#include <hip/hip_bf16.h>

#define MDIM 4096
#define KDIM 4096
#define NDIM 11008

#define BM 128
#define BN 128
#define BK 128            // int8 elements along K per LDS tile (=128 bytes/row)
#define NT (KDIM / BK)    // 32 K-steps

typedef int v4i __attribute__((ext_vector_type(4)));

__device__ __forceinline__ void gload_lds16(const void* g, void* s) {
  __builtin_amdgcn_global_load_lds(
      (const __attribute__((address_space(1))) void*)g,
      (__attribute__((address_space(3))) void*)s, 16, 0, 0);
}

// ---------------------------------------------------------------------------
// Kernel 1: per-token dynamic int8 quant of f32 x -> q[M,K] int8, scale[M] f32
// one block (256 threads) per row; 16 f32 elems/thread (4x float4)
// ---------------------------------------------------------------------------
__global__ __launch_bounds__(256) void quant_kernel(
    const float* __restrict__ x,           // f32 [M,K] (fp16 upcast by harness)
    unsigned* __restrict__ q,              // int8 out [M,K], 4 per word
    float* __restrict__ scales)            // f32 out [M]
{
  const int row = blockIdx.x;
  const int tid = threadIdx.x;
  const float4* xr = (const float4*)(x + (size_t)row * KDIM);
  float4 v[4];
#pragma unroll
  for (int i = 0; i < 4; ++i) v[i] = xr[tid + i * 256];

  float amax = 0.f;
#pragma unroll
  for (int i = 0; i < 4; ++i) {
    amax = fmaxf(amax, fmaxf(fmaxf(fabsf(v[i].x), fabsf(v[i].y)),
                             fmaxf(fabsf(v[i].z), fabsf(v[i].w))));
  }
  // wave reduction (64 lanes)
#pragma unroll
  for (int off = 32; off >= 1; off >>= 1)
    amax = fmaxf(amax, __shfl_xor(amax, off));
  __shared__ float red[4];
  const int lane = tid & 63, wv = tid >> 6;
  if (lane == 0) red[wv] = amax;
  __syncthreads();
  amax = fmaxf(fmaxf(red[0], red[1]), fmaxf(red[2], red[3]));

  const float scale = fmaxf(amax, 1e-7f) * (1.0f / 127.0f);
  const float rs = 1.0f / scale;
  if (tid == 0) scales[row] = scale;

#pragma unroll
  for (int i = 0; i < 4; ++i) {
    float e[4] = {v[i].x, v[i].y, v[i].z, v[i].w};
    unsigned w = 0;
#pragma unroll
    for (int j = 0; j < 4; ++j) {
      float qf = rintf(e[j] * rs);          // round-half-even like jnp.round
      qf = fminf(fmaxf(qf, -128.f), 127.f);
      int qi = (int)qf;
      w |= ((unsigned)(qi & 255)) << (8 * j);
    }
    q[(size_t)row * (KDIM / 4) + tid + i * 256] = w;
  }
}

// ---------------------------------------------------------------------------
// Kernel 2: pack int32 weight [N,K] -> int8 [N,K]
// ---------------------------------------------------------------------------
__global__ __launch_bounds__(256) void pack_kernel(
    const int4* __restrict__ w32, unsigned* __restrict__ w8, int n_units)
{
  int idx = blockIdx.x * 256 + threadIdx.x;
  const int stride = gridDim.x * 256;
  for (; idx < n_units; idx += stride) {
    int4 v = w32[idx];
    unsigned d = ((unsigned)(v.x & 255)) | ((unsigned)(v.y & 255) << 8) |
                 ((unsigned)(v.z & 255) << 16) | ((unsigned)(v.w & 255) << 24);
    w8[idx] = d;
  }
}

// ---------------------------------------------------------------------------
// Kernel 3a: int8 GEMM (packed-weight path).
// out[m,n] = (sum_k q[m,k]*w[n,k]) * is[m] * ws[n] + bias[n], f32 out.
// 128x128 tile, BK=128, 4 waves (2x2), mfma_i32_16x16x64_i8, double-buffered,
// both operands staged via global_load_lds width=16 (m97 structure).
// ---------------------------------------------------------------------------
__global__ __launch_bounds__(256) void gemm_i8_kernel(
    const signed char* __restrict__ qa,   // [M,K] int8
    const signed char* __restrict__ wb,   // [N,K] int8
    const float* __restrict__ scales,     // [M]
    const float* __restrict__ wscale,     // [N]
    const float* __restrict__ bias,       // [N]
    float* __restrict__ out)              // [M,N] f32
{
  __shared__ __align__(16) signed char As[2][BM * BK];
  __shared__ __align__(16) signed char Bs[2][BN * BK];

  const int tid = threadIdx.x;
  const int lane = tid & 63;
  const int wv = tid >> 6;
  const int wm = wv >> 1;
  const int wn = wv & 1;

  const int n0 = blockIdx.x * BN;
  const int m0 = blockIdx.y * BM;

  const signed char* sA0 = &As[0][0];
  const signed char* sB0 = &Bs[0][0];

  auto stage = [&](int buf, int kt) {
#pragma unroll
    for (int it = 0; it < 4; ++it) {
      const int slot = it * 256 + tid;
      const int r = slot >> 3;          // row in tile
      const int c = slot & 7;           // 16B chunk in row
      const int ldso = (it * 256 + wv * 64) * 16;  // wave-uniform base
      gload_lds16(qa + (size_t)(m0 + r) * KDIM + (size_t)kt * BK + c * 16,
                  (void*)(sA0 + buf * BM * BK + ldso));
      gload_lds16(wb + (size_t)(n0 + r) * KDIM + (size_t)kt * BK + c * 16,
                  (void*)(sB0 + buf * BN * BK + ldso));
    }
  };

  v4i acc[4][4] = {};

  stage(0, 0);
  asm volatile("s_waitcnt vmcnt(0)" ::: "memory");
  __syncthreads();

  int cur = 0;
  for (int kt = 0; kt < NT; ++kt) {
    if (kt + 1 < NT) stage(cur ^ 1, kt + 1);

    const int rsel = lane & 15;
#pragma unroll
    for (int kk = 0; kk < 2; ++kk) {
      const int cbyte = (lane >> 4) * 16 + kk * 64;
      v4i af[4], bfr[4];
#pragma unroll
      for (int mi = 0; mi < 4; ++mi) {
        const int r = wm * 64 + mi * 16 + rsel;
        af[mi] = *(const v4i*)&As[cur][r * BK + cbyte];
      }
#pragma unroll
      for (int ni = 0; ni < 4; ++ni) {
        const int r = wn * 64 + ni * 16 + rsel;
        bfr[ni] = *(const v4i*)&Bs[cur][r * BK + cbyte];
      }
#pragma unroll
      for (int mi = 0; mi < 4; ++mi)
#pragma unroll
        for (int ni = 0; ni < 4; ++ni)
          acc[mi][ni] = __builtin_amdgcn_mfma_i32_16x16x64_i8(
              af[mi], bfr[ni], acc[mi][ni], 0, 0, 0);
    }
    asm volatile("s_waitcnt vmcnt(0)" ::: "memory");
    __syncthreads();
    cur ^= 1;
  }

  const int cl = lane & 15;
  const int rb = (lane >> 4) * 4;
#pragma unroll
  for (int ni = 0; ni < 4; ++ni) {
    const int n = n0 + wn * 64 + ni * 16 + cl;
    const float wsc = wscale[n];
    const float bs = bias[n];
#pragma unroll
    for (int mi = 0; mi < 4; ++mi) {
      const int mb = m0 + wm * 64 + mi * 16 + rb;
#pragma unroll
      for (int j = 0; j < 4; ++j) {
        const int m = mb + j;
        out[(size_t)m * NDIM + n] =
            (float)acc[mi][ni][j] * scales[m] * wsc + bs;
      }
    }
  }
}

// ---------------------------------------------------------------------------
// Kernel 3b: fallback — weight consumed directly as int32 (reg-staged pack).
// ---------------------------------------------------------------------------
__global__ __launch_bounds__(256) void gemm_w32_kernel(
    const signed char* __restrict__ qa,   // [M,K] int8
    const int* __restrict__ w32,          // [N,K] int32
    const float* __restrict__ scales,
    const float* __restrict__ wscale,
    const float* __restrict__ bias,
    float* __restrict__ out)
{
  __shared__ __align__(16) signed char As[2][BM * BK];
  __shared__ __align__(16) signed char Bs[2][BN * BK];

  const int tid = threadIdx.x;
  const int lane = tid & 63;
  const int wv = tid >> 6;
  const int wm = wv >> 1;
  const int wn = wv & 1;

  const int n0 = blockIdx.x * BN;
  const int m0 = blockIdx.y * BM;

  const signed char* sA0 = &As[0][0];

  auto stageA = [&](int buf, int kt) {
#pragma unroll
    for (int it = 0; it < 4; ++it) {
      const int slot = it * 256 + tid;
      const int r = slot >> 3;
      const int c = slot & 7;
      const int ldso = (it * 256 + wv * 64) * 16;
      gload_lds16(qa + (size_t)(m0 + r) * KDIM + (size_t)kt * BK + c * 16,
                  (void*)(sA0 + buf * BM * BK + ldso));
    }
  };
  auto loadB = [&](int kt, int4* regs) {
#pragma unroll
    for (int it = 0; it < 4; ++it) {
      const int slot = it * 256 + tid;
      const int r = slot >> 3;
      const int c = slot & 7;
      const int4* src =
          (const int4*)(w32 + (size_t)(n0 + r) * KDIM + (size_t)kt * BK + c * 16);
#pragma unroll
      for (int j = 0; j < 4; ++j) regs[it * 4 + j] = src[j];
    }
  };
  auto writeB = [&](int buf, const int4* regs) {
#pragma unroll
    for (int it = 0; it < 4; ++it) {
      const int slot = it * 256 + tid;
      const int r = slot >> 3;
      const int c = slot & 7;
      unsigned d[4];
#pragma unroll
      for (int j = 0; j < 4; ++j) {
        int4 v = regs[it * 4 + j];
        d[j] = ((unsigned)(v.x & 255)) | ((unsigned)(v.y & 255) << 8) |
               ((unsigned)(v.z & 255) << 16) | ((unsigned)(v.w & 255) << 24);
      }
      *(uint4*)&Bs[buf][r * BK + c * 16] = make_uint4(d[0], d[1], d[2], d[3]);
    }
  };

  v4i acc[4][4] = {};
  int4 bregs[16];

  stageA(0, 0);
  loadB(0, bregs);
  writeB(0, bregs);
  asm volatile("s_waitcnt vmcnt(0)" ::: "memory");
  __syncthreads();

  int cur = 0;
  for (int kt = 0; kt < NT; ++kt) {
    if (kt + 1 < NT) {
      stageA(cur ^ 1, kt + 1);
      loadB(kt + 1, bregs);
    }

    const int rsel = lane & 15;
#pragma unroll
    for (int kk = 0; kk < 2; ++kk) {
      const int cbyte = (lane >> 4) * 16 + kk * 64;
      v4i af[4], bfr[4];
#pragma unroll
      for (int mi = 0; mi < 4; ++mi) {
        const int r = wm * 64 + mi * 16 + rsel;
        af[mi] = *(const v4i*)&As[cur][r * BK + cbyte];
      }
#pragma unroll
      for (int ni = 0; ni < 4; ++ni) {
        const int r = wn * 64 + ni * 16 + rsel;
        bfr[ni] = *(const v4i*)&Bs[cur][r * BK + cbyte];
      }
#pragma unroll
      for (int mi = 0; mi < 4; ++mi)
#pragma unroll
        for (int ni = 0; ni < 4; ++ni)
          acc[mi][ni] = __builtin_amdgcn_mfma_i32_16x16x64_i8(
              af[mi], bfr[ni], acc[mi][ni], 0, 0, 0);
    }

    if (kt + 1 < NT) writeB(cur ^ 1, bregs);

    asm volatile("s_waitcnt vmcnt(0)" ::: "memory");
    __syncthreads();
    cur ^= 1;
  }

  const int cl = lane & 15;
  const int rb = (lane >> 4) * 4;
#pragma unroll
  for (int ni = 0; ni < 4; ++ni) {
    const int n = n0 + wn * 64 + ni * 16 + cl;
    const float wsc = wscale[n];
    const float bs = bias[n];
#pragma unroll
    for (int mi = 0; mi < 4; ++mi) {
      const int mb = m0 + wm * 64 + mi * 16 + rb;
#pragma unroll
      for (int j = 0; j < 4; ++j) {
        const int m = mb + j;
        out[(size_t)m * NDIM + n] =
            (float)acc[mi][ni][j] * scales[m] * wsc + bs;
      }
    }
  }
}

// ---------------------------------------------------------------------------
extern "C" void kernel_launch(void* const* d_in, const int* in_sizes, int n_in,
                              void* d_out, int out_size, void* d_ws, size_t ws_size,
                              hipStream_t stream) {
  const float* x = (const float*)d_in[0];        // f32 [M,K] (fp16 upcast)
  const int* w32 = (const int*)d_in[1];          // int32 [N,K]
  const float* wscale = (const float*)d_in[2];   // [N]
  const float* bias = (const float*)d_in[3];     // [N]
  float* out = (float*)d_out;                    // f32 [M,N]

  // workspace layout
  float* scales = (float*)d_ws;                                  // 16 KB slot
  signed char* qbuf = (signed char*)d_ws + 16384;                // M*K int8
  signed char* wpack = (signed char*)d_ws + 16384 + (size_t)MDIM * KDIM;

  const size_t need_pack =
      16384 + (size_t)MDIM * KDIM + (size_t)NDIM * KDIM;  // ~62 MB

  quant_kernel<<<MDIM, 256, 0, stream>>>(x, (unsigned*)qbuf, scales);

  dim3 grid(NDIM / BN, MDIM / BM);
  if (ws_size >= need_pack) {
    const int n_units = (NDIM * KDIM) / 4;
    pack_kernel<<<2048, 256, 0, stream>>>((const int4*)w32, (unsigned*)wpack,
                                          n_units);
    gemm_i8_kernel<<<grid, 256, 0, stream>>>(qbuf, wpack, scales, wscale, bias,
                                             out);
  } else {
    gemm_w32_kernel<<<grid, 256, 0, stream>>>(qbuf, w32, scales, wscale, bias,
                                              out);
  }
}

// Round 4
// 415.214 us; speedup vs baseline: 1.0685x; 1.0685x over previous
//
#include <hip/hip_runtime.h>
#include <hip/hip_bf16.h>

#define MDIM 4096
#define KDIM 4096
#define NDIM 11008

#define BM 128
#define BN 128
#define BK 64             // int8 elements along K per LDS tile (=64 bytes/row)
#define NT (KDIM / BK)    // 64 K-steps

typedef int v4i __attribute__((ext_vector_type(4)));

__device__ __forceinline__ void gload_lds16(const void* g, void* s) {
  __builtin_amdgcn_global_load_lds(
      (const __attribute__((address_space(1))) void*)g,
      (__attribute__((address_space(3))) void*)s, 16, 0, 0);
}

// ---------------------------------------------------------------------------
// Kernel 1: per-token dynamic int8 quant of f32 x -> q[M,K] int8, scale[M] f32
// one block (256 threads) per row; 16 f32 elems/thread (4x float4)
// ---------------------------------------------------------------------------
__global__ __launch_bounds__(256) void quant_kernel(
    const float* __restrict__ x,           // f32 [M,K] (fp16 upcast by harness)
    unsigned* __restrict__ q,              // int8 out [M,K], 4 per word
    float* __restrict__ scales)            // f32 out [M]
{
  const int row = blockIdx.x;
  const int tid = threadIdx.x;
  const float4* xr = (const float4*)(x + (size_t)row * KDIM);
  float4 v[4];
#pragma unroll
  for (int i = 0; i < 4; ++i) v[i] = xr[tid + i * 256];

  float amax = 0.f;
#pragma unroll
  for (int i = 0; i < 4; ++i) {
    amax = fmaxf(amax, fmaxf(fmaxf(fabsf(v[i].x), fabsf(v[i].y)),
                             fmaxf(fabsf(v[i].z), fabsf(v[i].w))));
  }
  // wave reduction (64 lanes)
#pragma unroll
  for (int off = 32; off >= 1; off >>= 1)
    amax = fmaxf(amax, __shfl_xor(amax, off));
  __shared__ float red[4];
  const int lane = tid & 63, wv = tid >> 6;
  if (lane == 0) red[wv] = amax;
  __syncthreads();
  amax = fmaxf(fmaxf(red[0], red[1]), fmaxf(red[2], red[3]));

  const float scale = fmaxf(amax, 1e-7f) * (1.0f / 127.0f);
  const float rs = 1.0f / scale;
  if (tid == 0) scales[row] = scale;

#pragma unroll
  for (int i = 0; i < 4; ++i) {
    float e[4] = {v[i].x, v[i].y, v[i].z, v[i].w};
    unsigned w = 0;
#pragma unroll
    for (int j = 0; j < 4; ++j) {
      float qf = rintf(e[j] * rs);          // round-half-even like jnp.round
      qf = fminf(fmaxf(qf, -128.f), 127.f);
      int qi = (int)qf;
      w |= ((unsigned)(qi & 255)) << (8 * j);
    }
    q[(size_t)row * (KDIM / 4) + tid + i * 256] = w;
  }
}

// ---------------------------------------------------------------------------
// Kernel 2: pack int32 weight [N,K] -> int8 [N,K]
// ---------------------------------------------------------------------------
__global__ __launch_bounds__(256) void pack_kernel(
    const int4* __restrict__ w32, unsigned* __restrict__ w8, int n_units)
{
  int idx = blockIdx.x * 256 + threadIdx.x;
  const int stride = gridDim.x * 256;
  for (; idx < n_units; idx += stride) {
    int4 v = w32[idx];
    unsigned d = ((unsigned)(v.x & 255)) | ((unsigned)(v.y & 255) << 8) |
                 ((unsigned)(v.z & 255) << 16) | ((unsigned)(v.w & 255) << 24);
    w8[idx] = d;
  }
}

// ---------------------------------------------------------------------------
// Kernel 3: int8 GEMM. out[m,n] = (sum_k q[m,k]*w[n,k]) * is[m] * ws[n] + b[n]
// 128x128 tile, BK=64 bytes (32 KB LDS total -> 4-5 blocks/CU), 4 waves (2x2),
// mfma_i32_16x16x64_i8, double-buffered, both operands staged via
// global_load_lds width=16 (verified m97 byte-geometry).
// ---------------------------------------------------------------------------
__global__ __launch_bounds__(256) void gemm_i8_kernel(
    const signed char* __restrict__ qa,   // [M,K] int8
    const signed char* __restrict__ wb,   // [N,K] int8
    const float* __restrict__ scales,     // [M]
    const float* __restrict__ wscale,     // [N]
    const float* __restrict__ bias,       // [N]
    float* __restrict__ out)              // [M,N] f32
{
  __shared__ __align__(16) signed char As[2][BM * BK];   // 2 x 8 KB
  __shared__ __align__(16) signed char Bs[2][BN * BK];   // 2 x 8 KB

  const int tid = threadIdx.x;
  const int lane = tid & 63;
  const int wv = tid >> 6;
  const int wm = wv >> 1;
  const int wn = wv & 1;

  const int n0 = blockIdx.x * BN;
  const int m0 = blockIdx.y * BM;

  const signed char* sA0 = &As[0][0];
  const signed char* sB0 = &Bs[0][0];

  // stage one K-tile: per operand 128 rows x 64 B = 512 16B-chunks, 2 iters
  auto stage = [&](int buf, int kt) {
#pragma unroll
    for (int it = 0; it < 2; ++it) {
      const int slot = it * 256 + tid;     // 0..511
      const int r = slot >> 2;             // row in tile (0..127)
      const int c = slot & 3;              // 16B chunk in row (0..3)
      const int ldso = (it * 256 + wv * 64) * 16;  // wave-uniform base
      gload_lds16(qa + (size_t)(m0 + r) * KDIM + (size_t)kt * BK + c * 16,
                  (void*)(sA0 + buf * BM * BK + ldso));
      gload_lds16(wb + (size_t)(n0 + r) * KDIM + (size_t)kt * BK + c * 16,
                  (void*)(sB0 + buf * BN * BK + ldso));
    }
  };

  v4i acc[4][4] = {};

  stage(0, 0);
  asm volatile("s_waitcnt vmcnt(0)" ::: "memory");
  __syncthreads();

  int cur = 0;
  for (int kt = 0; kt < NT; ++kt) {
    if (kt + 1 < NT) stage(cur ^ 1, kt + 1);

    const int rsel = lane & 15;
    const int cbyte = (lane >> 4) * 16;    // K-chunk within 64B row
    v4i af[4], bfr[4];
#pragma unroll
    for (int mi = 0; mi < 4; ++mi) {
      const int r = wm * 64 + mi * 16 + rsel;
      af[mi] = *(const v4i*)&As[cur][r * BK + cbyte];
    }
#pragma unroll
    for (int ni = 0; ni < 4; ++ni) {
      const int r = wn * 64 + ni * 16 + rsel;
      bfr[ni] = *(const v4i*)&Bs[cur][r * BK + cbyte];
    }
#pragma unroll
    for (int mi = 0; mi < 4; ++mi)
#pragma unroll
      for (int ni = 0; ni < 4; ++ni)
        acc[mi][ni] = __builtin_amdgcn_mfma_i32_16x16x64_i8(
            af[mi], bfr[ni], acc[mi][ni], 0, 0, 0);

    asm volatile("s_waitcnt vmcnt(0)" ::: "memory");
    __syncthreads();
    cur ^= 1;
  }

  // epilogue: dequant + bias, f32 store
  const int cl = lane & 15;          // col within 16x16 frag (N dir)
  const int rb = (lane >> 4) * 4;    // row base within frag (M dir)
#pragma unroll
  for (int ni = 0; ni < 4; ++ni) {
    const int n = n0 + wn * 64 + ni * 16 + cl;
    const float wsc = wscale[n];
    const float bs = bias[n];
#pragma unroll
    for (int mi = 0; mi < 4; ++mi) {
      const int mb = m0 + wm * 64 + mi * 16 + rb;
#pragma unroll
      for (int j = 0; j < 4; ++j) {
        const int m = mb + j;
        out[(size_t)m * NDIM + n] =
            (float)acc[mi][ni][j] * scales[m] * wsc + bs;
      }
    }
  }
}

// ---------------------------------------------------------------------------
extern "C" void kernel_launch(void* const* d_in, const int* in_sizes, int n_in,
                              void* d_out, int out_size, void* d_ws, size_t ws_size,
                              hipStream_t stream) {
  const float* x = (const float*)d_in[0];        // f32 [M,K] (fp16 upcast)
  const int* w32 = (const int*)d_in[1];          // int32 [N,K]
  const float* wscale = (const float*)d_in[2];   // [N]
  const float* bias = (const float*)d_in[3];     // [N]
  float* out = (float*)d_out;                    // f32 [M,N]

  // workspace layout (~62 MB; measured ws_size is sufficient — packed branch
  // was taken and passed in round 3)
  float* scales = (float*)d_ws;                                  // 16 KB slot
  signed char* qbuf = (signed char*)d_ws + 16384;                // M*K int8
  signed char* wpack = (signed char*)d_ws + 16384 + (size_t)MDIM * KDIM;

  quant_kernel<<<MDIM, 256, 0, stream>>>(x, (unsigned*)qbuf, scales);

  const int n_units = (NDIM * KDIM) / 4;
  pack_kernel<<<2048, 256, 0, stream>>>((const int4*)w32, (unsigned*)wpack,
                                        n_units);

  dim3 grid(NDIM / BN, MDIM / BM);
  gemm_i8_kernel<<<grid, 256, 0, stream>>>(qbuf, wpack, scales, wscale, bias,
                                           out);
}

// Round 5
// 328.420 us; speedup vs baseline: 1.3509x; 1.2643x over previous
//
#include <hip/hip_runtime.h>
#include <hip/hip_bf16.h>

#define MDIM 4096
#define KDIM 4096
#define NDIM 11008

#define BM 256
#define BN 256
#define BK 128            // int8 elements per K-tile (two K=64 MFMA slices)
#define NT (KDIM / BK)    // 32 K-tiles

typedef int v4i __attribute__((ext_vector_type(4)));

__device__ __forceinline__ void gload_lds16(const void* g, void* s) {
  __builtin_amdgcn_global_load_lds(
      (const __attribute__((address_space(1))) void*)g,
      (__attribute__((address_space(3))) void*)s, 16, 0, 0);
}

// ---------------------------------------------------------------------------
// Kernel 1: per-token dynamic int8 quant of f32 x -> q[M,K] int8, scale[M] f32
// ---------------------------------------------------------------------------
__global__ __launch_bounds__(256) void quant_kernel(
    const float* __restrict__ x,
    unsigned* __restrict__ q,
    float* __restrict__ scales)
{
  const int row = blockIdx.x;
  const int tid = threadIdx.x;
  const float4* xr = (const float4*)(x + (size_t)row * KDIM);
  float4 v[4];
#pragma unroll
  for (int i = 0; i < 4; ++i) v[i] = xr[tid + i * 256];

  float amax = 0.f;
#pragma unroll
  for (int i = 0; i < 4; ++i) {
    amax = fmaxf(amax, fmaxf(fmaxf(fabsf(v[i].x), fabsf(v[i].y)),
                             fmaxf(fabsf(v[i].z), fabsf(v[i].w))));
  }
#pragma unroll
  for (int off = 32; off >= 1; off >>= 1)
    amax = fmaxf(amax, __shfl_xor(amax, off));
  __shared__ float red[4];
  const int lane = tid & 63, wv = tid >> 6;
  if (lane == 0) red[wv] = amax;
  __syncthreads();
  amax = fmaxf(fmaxf(red[0], red[1]), fmaxf(red[2], red[3]));

  const float scale = fmaxf(amax, 1e-7f) * (1.0f / 127.0f);
  const float rs = 1.0f / scale;
  if (tid == 0) scales[row] = scale;

#pragma unroll
  for (int i = 0; i < 4; ++i) {
    float e[4] = {v[i].x, v[i].y, v[i].z, v[i].w};
    unsigned w = 0;
#pragma unroll
    for (int j = 0; j < 4; ++j) {
      float qf = rintf(e[j] * rs);
      qf = fminf(fmaxf(qf, -128.f), 127.f);
      int qi = (int)qf;
      w |= ((unsigned)(qi & 255)) << (8 * j);
    }
    q[(size_t)row * (KDIM / 4) + tid + i * 256] = w;
  }
}

// ---------------------------------------------------------------------------
// Kernel 2: pack int32 weight [N,K] -> int8 [N,K]
// ---------------------------------------------------------------------------
__global__ __launch_bounds__(256) void pack_kernel(
    const int4* __restrict__ w32, unsigned* __restrict__ w8, int n_units)
{
  int idx = blockIdx.x * 256 + threadIdx.x;
  const int stride = gridDim.x * 256;
  for (; idx < n_units; idx += stride) {
    int4 v = w32[idx];
    unsigned d = ((unsigned)(v.x & 255)) | ((unsigned)(v.y & 255) << 8) |
                 ((unsigned)(v.z & 255) << 16) | ((unsigned)(v.w & 255) << 24);
    w8[idx] = d;
  }
}

// ---------------------------------------------------------------------------
// Kernel 3: int8 GEMM, 256x256 tile, 8-phase schedule (T2+T3+T4+T5 port).
// 512 threads = 8 waves (2M x 4N); per-wave output 128x64.
// LDS: [2 dbuf][2 K-half][256 rows][64 B] per operand = 128 KiB total.
// Per K-tile: 4 phases; stage 1 half-tile/phase for tile t+1; vmcnt(4) at
// phase 2 & 4 only (never 0 in main loop). Swizzle: 16B-chunk c ^= (r&3),
// applied on the global source (gload_lds writes linearly) and on ds_read.
// ---------------------------------------------------------------------------
__global__ __launch_bounds__(512, 2) void gemm_i8_kernel(
    const signed char* __restrict__ qa,   // [M,K] int8
    const signed char* __restrict__ wb,   // [N,K] int8
    const float* __restrict__ scales,     // [M]
    const float* __restrict__ wscale,     // [N]
    const float* __restrict__ bias,       // [N]
    float* __restrict__ out)              // [M,N] f32
{
  __shared__ __align__(16) signed char As[2][2][256 * 64];  // 64 KiB
  __shared__ __align__(16) signed char Bs[2][2][256 * 64];  // 64 KiB

  const int tid = threadIdx.x;
  const int lane = tid & 63;
  const int wv = tid >> 6;       // 0..7
  const int wr = wv >> 2;        // 0..1 (M half)
  const int wc = wv & 3;         // 0..3 (N quarter)

  const int n0 = blockIdx.x * BN;
  const int m0 = blockIdx.y * BM;

  const signed char* Ag = qa + (size_t)m0 * KDIM;
  const signed char* Bg = wb + (size_t)n0 * KDIM;

  // stage one 16 KiB half-tile (rows 0..255 x 64 B of K-half kh) for tile kt.
  // LDS dest is linear (wave-uniform base, HW appends lane*16); the swizzle
  // is applied by permuting the GLOBAL source chunk: c_g = c_lds ^ (r & 3).
  auto stageH = [&](signed char* dst, const signed char* g, int kt, int kh) {
#pragma unroll
    for (int i = 0; i < 2; ++i) {
      const int chunk = i * 512 + tid;          // 0..1023
      const int r = chunk >> 2;                 // row 0..255
      const int cg = (chunk & 3) ^ (r & 3);     // swizzled global chunk
      gload_lds16(g + (size_t)r * KDIM + (size_t)kt * BK + kh * 64 + cg * 16,
                  dst + (i * 512 + wv * 64) * 16);
    }
  };

  // fragment reads (swizzled): global chunk ksel at row r lives at LDS chunk
  // ksel ^ (r&3); r&3 == lane&3 for all our frag rows (bases are mult. of 16).
  const int swz16 = (((lane >> 4) ^ (lane & 3)) << 4);
  const int frow_a = wr * 128 + (lane & 15);
  const int frow_b = wc * 64 + (lane & 15);

  auto ardA = [&](const signed char* plane, int mi) -> v4i {
    return *(const v4i*)(plane + (frow_a + mi * 16) * 64 + swz16);
  };
  auto ardB = [&](const signed char* plane, int ni) -> v4i {
    return *(const v4i*)(plane + (frow_b + ni * 16) * 64 + swz16);
  };

  v4i acc[8][4] = {};
  v4i bfrag[4];

  // prologue: tile 0, issue order A-kh0, B-kh0, A-kh1, B-kh1 (8 loads)
  stageH(&As[0][0][0], Ag, 0, 0);
  stageH(&Bs[0][0][0], Bg, 0, 0);
  stageH(&As[0][1][0], Ag, 0, 1);
  stageH(&Bs[0][1][0], Bg, 0, 1);
  asm volatile("s_waitcnt vmcnt(4)" ::: "memory");  // kh0 pair resident
  __builtin_amdgcn_s_barrier();

  for (int t = 0; t < NT; ++t) {
    const int cur = t & 1;
    const int nxt = cur ^ 1;
    const bool pf = (t + 1 < NT);
    const signed char* A0 = &As[cur][0][0];
    const signed char* A1 = &As[cur][1][0];
    const signed char* B0 = &Bs[cur][0][0];
    const signed char* B1 = &Bs[cur][1][0];
    v4i af[4];

    // ---------- phase 1: kk0, frag rows 0-3 ----------
#pragma unroll
    for (int mi = 0; mi < 4; ++mi) af[mi] = ardA(A0, mi);
#pragma unroll
    for (int ni = 0; ni < 4; ++ni) bfrag[ni] = ardB(B0, ni);
    if (pf) stageH(&As[nxt][0][0], Ag, t + 1, 0);
    __builtin_amdgcn_sched_barrier(0);
    __builtin_amdgcn_s_barrier();
    asm volatile("s_waitcnt lgkmcnt(0)" ::: "memory");
    __builtin_amdgcn_sched_barrier(0);
    __builtin_amdgcn_s_setprio(1);
#pragma unroll
    for (int mi = 0; mi < 4; ++mi)
#pragma unroll
      for (int ni = 0; ni < 4; ++ni)
        acc[mi][ni] = __builtin_amdgcn_mfma_i32_16x16x64_i8(
            af[mi], bfrag[ni], acc[mi][ni], 0, 0, 0);
    __builtin_amdgcn_s_setprio(0);
    __builtin_amdgcn_sched_barrier(0);
    __builtin_amdgcn_s_barrier();

    // ---------- phase 2: kk0, frag rows 4-7 ----------
#pragma unroll
    for (int mi = 0; mi < 4; ++mi) af[mi] = ardA(A0, mi + 4);
    if (pf) stageH(&Bs[nxt][0][0], Bg, t + 1, 0);
    __builtin_amdgcn_sched_barrier(0);
    __builtin_amdgcn_s_barrier();
    asm volatile("s_waitcnt lgkmcnt(0)" ::: "memory");
    __builtin_amdgcn_sched_barrier(0);
    __builtin_amdgcn_s_setprio(1);
#pragma unroll
    for (int mi = 0; mi < 4; ++mi)
#pragma unroll
      for (int ni = 0; ni < 4; ++ni)
        acc[mi + 4][ni] = __builtin_amdgcn_mfma_i32_16x16x64_i8(
            af[mi], bfrag[ni], acc[mi + 4][ni], 0, 0, 0);
    __builtin_amdgcn_s_setprio(0);
    __builtin_amdgcn_sched_barrier(0);
    // drain this tile's kh1 pair (staged during tile t-1); keep 4 in flight
    if (pf) { asm volatile("s_waitcnt vmcnt(4)" ::: "memory"); }
    else    { asm volatile("s_waitcnt vmcnt(0)" ::: "memory"); }
    __builtin_amdgcn_s_barrier();

    // ---------- phase 3: kk1, frag rows 0-3 ----------
#pragma unroll
    for (int mi = 0; mi < 4; ++mi) af[mi] = ardA(A1, mi);
#pragma unroll
    for (int ni = 0; ni < 4; ++ni) bfrag[ni] = ardB(B1, ni);
    if (pf) stageH(&As[nxt][1][0], Ag, t + 1, 1);
    __builtin_amdgcn_sched_barrier(0);
    __builtin_amdgcn_s_barrier();
    asm volatile("s_waitcnt lgkmcnt(0)" ::: "memory");
    __builtin_amdgcn_sched_barrier(0);
    __builtin_amdgcn_s_setprio(1);
#pragma unroll
    for (int mi = 0; mi < 4; ++mi)
#pragma unroll
      for (int ni = 0; ni < 4; ++ni)
        acc[mi][ni] = __builtin_amdgcn_mfma_i32_16x16x64_i8(
            af[mi], bfrag[ni], acc[mi][ni], 0, 0, 0);
    __builtin_amdgcn_s_setprio(0);
    __builtin_amdgcn_sched_barrier(0);
    __builtin_amdgcn_s_barrier();

    // ---------- phase 4: kk1, frag rows 4-7 ----------
#pragma unroll
    for (int mi = 0; mi < 4; ++mi) af[mi] = ardA(A1, mi + 4);
    if (pf) stageH(&Bs[nxt][1][0], Bg, t + 1, 1);
    __builtin_amdgcn_sched_barrier(0);
    __builtin_amdgcn_s_barrier();
    asm volatile("s_waitcnt lgkmcnt(0)" ::: "memory");
    __builtin_amdgcn_sched_barrier(0);
    __builtin_amdgcn_s_setprio(1);
#pragma unroll
    for (int mi = 0; mi < 4; ++mi)
#pragma unroll
      for (int ni = 0; ni < 4; ++ni)
        acc[mi + 4][ni] = __builtin_amdgcn_mfma_i32_16x16x64_i8(
            af[mi], bfrag[ni], acc[mi + 4][ni], 0, 0, 0);
    __builtin_amdgcn_s_setprio(0);
    __builtin_amdgcn_sched_barrier(0);
    // drain next tile's kh0 pair; keep its kh1 pair (4 loads) in flight
    if (pf) { asm volatile("s_waitcnt vmcnt(4)" ::: "memory"); }
    __builtin_amdgcn_s_barrier();
  }

  // epilogue: dequant + bias, f32 store
  const int cl = lane & 15;
  const int rb = (lane >> 4) * 4;
#pragma unroll
  for (int ni = 0; ni < 4; ++ni) {
    const int n = n0 + wc * 64 + ni * 16 + cl;
    const float wsc = wscale[n];
    const float bs = bias[n];
#pragma unroll
    for (int mi = 0; mi < 8; ++mi) {
      const int mb = m0 + wr * 128 + mi * 16 + rb;
#pragma unroll
      for (int j = 0; j < 4; ++j) {
        const int m = mb + j;
        out[(size_t)m * NDIM + n] =
            (float)acc[mi][ni][j] * scales[m] * wsc + bs;
      }
    }
  }
}

// ---------------------------------------------------------------------------
extern "C" void kernel_launch(void* const* d_in, const int* in_sizes, int n_in,
                              void* d_out, int out_size, void* d_ws, size_t ws_size,
                              hipStream_t stream) {
  const float* x = (const float*)d_in[0];        // f32 [M,K] (fp16 upcast)
  const int* w32 = (const int*)d_in[1];          // int32 [N,K]
  const float* wscale = (const float*)d_in[2];   // [N]
  const float* bias = (const float*)d_in[3];     // [N]
  float* out = (float*)d_out;                    // f32 [M,N]

  float* scales = (float*)d_ws;                                  // 16 KB slot
  signed char* qbuf = (signed char*)d_ws + 16384;                // M*K int8
  signed char* wpack = (signed char*)d_ws + 16384 + (size_t)MDIM * KDIM;

  quant_kernel<<<MDIM, 256, 0, stream>>>(x, (unsigned*)qbuf, scales);

  const int n_units = (NDIM * KDIM) / 4;
  pack_kernel<<<2048, 256, 0, stream>>>((const int4*)w32, (unsigned*)wpack,
                                        n_units);

  dim3 grid(NDIM / BN, MDIM / BM);   // 43 x 16
  gemm_i8_kernel<<<grid, 512, 0, stream>>>(qbuf, wpack, scales, wscale, bias,
                                           out);
}

// Round 6
// 322.792 us; speedup vs baseline: 1.3744x; 1.0174x over previous
//
#include <hip/hip_runtime.h>
#include <hip/hip_bf16.h>

#define MDIM 4096
#define KDIM 4096
#define NDIM 11008

#define BM 256
#define BN 256
#define BK 128            // int8 elements per K-tile (two K=64 MFMA slices)
#define NT (KDIM / BK)    // 32 K-tiles

typedef int v4i __attribute__((ext_vector_type(4)));

__device__ __forceinline__ void gload_lds16(const void* g, void* s) {
  __builtin_amdgcn_global_load_lds(
      (const __attribute__((address_space(1))) void*)g,
      (__attribute__((address_space(3))) void*)s, 16, 0, 0);
}

// ---------------------------------------------------------------------------
// Kernel 1: per-token dynamic int8 quant of f32 x -> q[M,K] int8, scale[M] f32
// ---------------------------------------------------------------------------
__global__ __launch_bounds__(256) void quant_kernel(
    const float* __restrict__ x,
    unsigned* __restrict__ q,
    float* __restrict__ scales)
{
  const int row = blockIdx.x;
  const int tid = threadIdx.x;
  const float4* xr = (const float4*)(x + (size_t)row * KDIM);
  float4 v[4];
#pragma unroll
  for (int i = 0; i < 4; ++i) v[i] = xr[tid + i * 256];

  float amax = 0.f;
#pragma unroll
  for (int i = 0; i < 4; ++i) {
    amax = fmaxf(amax, fmaxf(fmaxf(fabsf(v[i].x), fabsf(v[i].y)),
                             fmaxf(fabsf(v[i].z), fabsf(v[i].w))));
  }
#pragma unroll
  for (int off = 32; off >= 1; off >>= 1)
    amax = fmaxf(amax, __shfl_xor(amax, off));
  __shared__ float red[4];
  const int lane = tid & 63, wv = tid >> 6;
  if (lane == 0) red[wv] = amax;
  __syncthreads();
  amax = fmaxf(fmaxf(red[0], red[1]), fmaxf(red[2], red[3]));

  const float scale = fmaxf(amax, 1e-7f) * (1.0f / 127.0f);
  const float rs = 1.0f / scale;
  if (tid == 0) scales[row] = scale;

#pragma unroll
  for (int i = 0; i < 4; ++i) {
    float e[4] = {v[i].x, v[i].y, v[i].z, v[i].w};
    unsigned w = 0;
#pragma unroll
    for (int j = 0; j < 4; ++j) {
      float qf = rintf(e[j] * rs);
      qf = fminf(fmaxf(qf, -128.f), 127.f);
      int qi = (int)qf;
      w |= ((unsigned)(qi & 255)) << (8 * j);
    }
    q[(size_t)row * (KDIM / 4) + tid + i * 256] = w;
  }
}

// ---------------------------------------------------------------------------
// Kernel 2: pack int32 weight [N,K] -> int8 [N,K]
// ---------------------------------------------------------------------------
__global__ __launch_bounds__(256) void pack_kernel(
    const int4* __restrict__ w32, unsigned* __restrict__ w8, int n_units)
{
  int idx = blockIdx.x * 256 + threadIdx.x;
  const int stride = gridDim.x * 256;
  for (; idx < n_units; idx += stride) {
    int4 v = w32[idx];
    unsigned d = ((unsigned)(v.x & 255)) | ((unsigned)(v.y & 255) << 8) |
                 ((unsigned)(v.z & 255) << 16) | ((unsigned)(v.w & 255) << 24);
    w8[idx] = d;
  }
}

// ---------------------------------------------------------------------------
// Kernel 3: int8 GEMM, 256x256 tile, 8-phase schedule (T2+T3+T4+T5).
// 512 threads = 8 waves (2M x 4N); per-wave output 128x64.
// LDS: [2 dbuf][2 K-half][256 rows][64 B] per operand = 128 KiB total.
// Swizzle: 16B-chunk c ^= ((r>>1)&3) — spreads each fragment-column read
// across all 8 bank groups (2-way residual = free, m136). Applied on the
// global source (gload_lds writes linearly) and on the ds_read address.
// vmcnt(4) at phase 2 & 4 only (never 0 in main loop).
// ---------------------------------------------------------------------------
__global__ __launch_bounds__(512, 2) void gemm_i8_kernel(
    const signed char* __restrict__ qa,   // [M,K] int8
    const signed char* __restrict__ wb,   // [N,K] int8
    const float* __restrict__ scales,     // [M]
    const float* __restrict__ wscale,     // [N]
    const float* __restrict__ bias,       // [N]
    float* __restrict__ out)              // [M,N] f32
{
  __shared__ __align__(16) signed char As[2][2][256 * 64];  // 64 KiB
  __shared__ __align__(16) signed char Bs[2][2][256 * 64];  // 64 KiB

  const int tid = threadIdx.x;
  const int lane = tid & 63;
  const int wv = tid >> 6;       // 0..7
  const int wr = wv >> 2;        // 0..1 (M half)
  const int wc = wv & 3;         // 0..3 (N quarter)

  const int n0 = blockIdx.x * BN;
  const int m0 = blockIdx.y * BM;

  const signed char* Ag = qa + (size_t)m0 * KDIM;
  const signed char* Bg = wb + (size_t)n0 * KDIM;

  // stage one 16 KiB half-tile (rows 0..255 x 64 B of K-half kh) for tile kt.
  // LDS dest linear (wave-uniform base + lane*16); swizzle via permuted
  // GLOBAL source chunk: c_g = c_lds ^ ((r>>1)&3).
  auto stageH = [&](signed char* dst, const signed char* g, int kt, int kh) {
#pragma unroll
    for (int i = 0; i < 2; ++i) {
      const int chunk = i * 512 + tid;            // 0..1023
      const int r = chunk >> 2;                   // row 0..255
      const int cg = (chunk & 3) ^ ((r >> 1) & 3);  // swizzled global chunk
      gload_lds16(g + (size_t)r * KDIM + (size_t)kt * BK + kh * 64 + cg * 16,
                  dst + (i * 512 + wv * 64) * 16);
    }
  };

  // fragment reads: global chunk ksel of row r lives at LDS chunk
  // ksel ^ ((r>>1)&3); all frag-row bases are multiples of 16, so
  // (r>>1)&3 == ((lane&15)>>1)&3 — compile-time per lane.
  const int swz16 = (((lane >> 4) ^ (((lane & 15) >> 1) & 3)) << 4);
  const int frow_a = wr * 128 + (lane & 15);
  const int frow_b = wc * 64 + (lane & 15);

  auto ardA = [&](const signed char* plane, int mi) -> v4i {
    return *(const v4i*)(plane + (frow_a + mi * 16) * 64 + swz16);
  };
  auto ardB = [&](const signed char* plane, int ni) -> v4i {
    return *(const v4i*)(plane + (frow_b + ni * 16) * 64 + swz16);
  };

  v4i acc[8][4] = {};
  v4i bfrag[4];

  // prologue: tile 0, issue order A-kh0, B-kh0, A-kh1, B-kh1 (8 loads)
  stageH(&As[0][0][0], Ag, 0, 0);
  stageH(&Bs[0][0][0], Bg, 0, 0);
  stageH(&As[0][1][0], Ag, 0, 1);
  stageH(&Bs[0][1][0], Bg, 0, 1);
  asm volatile("s_waitcnt vmcnt(4)" ::: "memory");  // kh0 pair resident
  __builtin_amdgcn_s_barrier();

  for (int t = 0; t < NT; ++t) {
    const int cur = t & 1;
    const int nxt = cur ^ 1;
    const bool pf = (t + 1 < NT);
    const signed char* A0 = &As[cur][0][0];
    const signed char* A1 = &As[cur][1][0];
    const signed char* B0 = &Bs[cur][0][0];
    const signed char* B1 = &Bs[cur][1][0];
    v4i af[4];

    // ---------- phase 1: kk0, frag rows 0-3 ----------
#pragma unroll
    for (int mi = 0; mi < 4; ++mi) af[mi] = ardA(A0, mi);
#pragma unroll
    for (int ni = 0; ni < 4; ++ni) bfrag[ni] = ardB(B0, ni);
    if (pf) stageH(&As[nxt][0][0], Ag, t + 1, 0);
    __builtin_amdgcn_sched_barrier(0);
    __builtin_amdgcn_s_barrier();
    asm volatile("s_waitcnt lgkmcnt(0)" ::: "memory");
    __builtin_amdgcn_sched_barrier(0);
    __builtin_amdgcn_s_setprio(1);
#pragma unroll
    for (int mi = 0; mi < 4; ++mi)
#pragma unroll
      for (int ni = 0; ni < 4; ++ni)
        acc[mi][ni] = __builtin_amdgcn_mfma_i32_16x16x64_i8(
            af[mi], bfrag[ni], acc[mi][ni], 0, 0, 0);
    __builtin_amdgcn_s_setprio(0);
    __builtin_amdgcn_sched_barrier(0);
    __builtin_amdgcn_s_barrier();

    // ---------- phase 2: kk0, frag rows 4-7 ----------
#pragma unroll
    for (int mi = 0; mi < 4; ++mi) af[mi] = ardA(A0, mi + 4);
    if (pf) stageH(&Bs[nxt][0][0], Bg, t + 1, 0);
    __builtin_amdgcn_sched_barrier(0);
    __builtin_amdgcn_s_barrier();
    asm volatile("s_waitcnt lgkmcnt(0)" ::: "memory");
    __builtin_amdgcn_sched_barrier(0);
    __builtin_amdgcn_s_setprio(1);
#pragma unroll
    for (int mi = 0; mi < 4; ++mi)
#pragma unroll
      for (int ni = 0; ni < 4; ++ni)
        acc[mi + 4][ni] = __builtin_amdgcn_mfma_i32_16x16x64_i8(
            af[mi], bfrag[ni], acc[mi + 4][ni], 0, 0, 0);
    __builtin_amdgcn_s_setprio(0);
    __builtin_amdgcn_sched_barrier(0);
    // drain this tile's kh1 pair (staged during tile t-1); keep 4 in flight
    if (pf) { asm volatile("s_waitcnt vmcnt(4)" ::: "memory"); }
    else    { asm volatile("s_waitcnt vmcnt(0)" ::: "memory"); }
    __builtin_amdgcn_s_barrier();

    // ---------- phase 3: kk1, frag rows 0-3 ----------
#pragma unroll
    for (int mi = 0; mi < 4; ++mi) af[mi] = ardA(A1, mi);
#pragma unroll
    for (int ni = 0; ni < 4; ++ni) bfrag[ni] = ardB(B1, ni);
    if (pf) stageH(&As[nxt][1][0], Ag, t + 1, 1);
    __builtin_amdgcn_sched_barrier(0);
    __builtin_amdgcn_s_barrier();
    asm volatile("s_waitcnt lgkmcnt(0)" ::: "memory");
    __builtin_amdgcn_sched_barrier(0);
    __builtin_amdgcn_s_setprio(1);
#pragma unroll
    for (int mi = 0; mi < 4; ++mi)
#pragma unroll
      for (int ni = 0; ni < 4; ++ni)
        acc[mi][ni] = __builtin_amdgcn_mfma_i32_16x16x64_i8(
            af[mi], bfrag[ni], acc[mi][ni], 0, 0, 0);
    __builtin_amdgcn_s_setprio(0);
    __builtin_amdgcn_sched_barrier(0);
    __builtin_amdgcn_s_barrier();

    // ---------- phase 4: kk1, frag rows 4-7 ----------
#pragma unroll
    for (int mi = 0; mi < 4; ++mi) af[mi] = ardA(A1, mi + 4);
    if (pf) stageH(&Bs[nxt][1][0], Bg, t + 1, 1);
    __builtin_amdgcn_sched_barrier(0);
    __builtin_amdgcn_s_barrier();
    asm volatile("s_waitcnt lgkmcnt(0)" ::: "memory");
    __builtin_amdgcn_sched_barrier(0);
    __builtin_amdgcn_s_setprio(1);
#pragma unroll
    for (int mi = 0; mi < 4; ++mi)
#pragma unroll
      for (int ni = 0; ni < 4; ++ni)
        acc[mi + 4][ni] = __builtin_amdgcn_mfma_i32_16x16x64_i8(
            af[mi], bfrag[ni], acc[mi + 4][ni], 0, 0, 0);
    __builtin_amdgcn_s_setprio(0);
    __builtin_amdgcn_sched_barrier(0);
    // drain next tile's kh0 pair; keep its kh1 pair (4 loads) in flight
    if (pf) { asm volatile("s_waitcnt vmcnt(4)" ::: "memory"); }
    __builtin_amdgcn_s_barrier();
  }

  // epilogue: dequant + bias, f32 store
  const int cl = lane & 15;
  const int rb = (lane >> 4) * 4;
#pragma unroll
  for (int ni = 0; ni < 4; ++ni) {
    const int n = n0 + wc * 64 + ni * 16 + cl;
    const float wsc = wscale[n];
    const float bs = bias[n];
#pragma unroll
    for (int mi = 0; mi < 8; ++mi) {
      const int mb = m0 + wr * 128 + mi * 16 + rb;
#pragma unroll
      for (int j = 0; j < 4; ++j) {
        const int m = mb + j;
        out[(size_t)m * NDIM + n] =
            (float)acc[mi][ni][j] * scales[m] * wsc + bs;
      }
    }
  }
}

// ---------------------------------------------------------------------------
extern "C" void kernel_launch(void* const* d_in, const int* in_sizes, int n_in,
                              void* d_out, int out_size, void* d_ws, size_t ws_size,
                              hipStream_t stream) {
  const float* x = (const float*)d_in[0];        // f32 [M,K] (fp16 upcast)
  const int* w32 = (const int*)d_in[1];          // int32 [N,K]
  const float* wscale = (const float*)d_in[2];   // [N]
  const float* bias = (const float*)d_in[3];     // [N]
  float* out = (float*)d_out;                    // f32 [M,N]

  float* scales = (float*)d_ws;                                  // 16 KB slot
  signed char* qbuf = (signed char*)d_ws + 16384;                // M*K int8
  signed char* wpack = (signed char*)d_ws + 16384 + (size_t)MDIM * KDIM;

  quant_kernel<<<MDIM, 256, 0, stream>>>(x, (unsigned*)qbuf, scales);

  const int n_units = (NDIM * KDIM) / 4;
  pack_kernel<<<2048, 256, 0, stream>>>((const int4*)w32, (unsigned*)wpack,
                                        n_units);

  dim3 grid(NDIM / BN, MDIM / BM);   // 43 x 16
  gemm_i8_kernel<<<grid, 512, 0, stream>>>(qbuf, wpack, scales, wscale, bias,
                                           out);
}

// Round 7
// 322.536 us; speedup vs baseline: 1.3755x; 1.0008x over previous
//
#include <hip/hip_runtime.h>
#include <hip/hip_bf16.h>

#define MDIM 4096
#define KDIM 4096
#define NDIM 11008

#define BM 256
#define BN 256
#define BK 128            // int8 elements per K-tile (two K=64 MFMA slices)
#define NT (KDIM / BK)    // 32 K-tiles

typedef int v4i __attribute__((ext_vector_type(4)));

__device__ __forceinline__ void gload_lds16(const void* g, void* s) {
  __builtin_amdgcn_global_load_lds(
      (const __attribute__((address_space(1))) void*)g,
      (__attribute__((address_space(3))) void*)s, 16, 0, 0);
}

// ---------------------------------------------------------------------------
// Kernel 1: per-token dynamic int8 quant of f32 x -> q[M,K] int8, scale[M] f32
// ---------------------------------------------------------------------------
__global__ __launch_bounds__(256) void quant_kernel(
    const float* __restrict__ x,
    unsigned* __restrict__ q,
    float* __restrict__ scales)
{
  const int row = blockIdx.x;
  const int tid = threadIdx.x;
  const float4* xr = (const float4*)(x + (size_t)row * KDIM);
  float4 v[4];
#pragma unroll
  for (int i = 0; i < 4; ++i) v[i] = xr[tid + i * 256];

  float amax = 0.f;
#pragma unroll
  for (int i = 0; i < 4; ++i) {
    amax = fmaxf(amax, fmaxf(fmaxf(fabsf(v[i].x), fabsf(v[i].y)),
                             fmaxf(fabsf(v[i].z), fabsf(v[i].w))));
  }
#pragma unroll
  for (int off = 32; off >= 1; off >>= 1)
    amax = fmaxf(amax, __shfl_xor(amax, off));
  __shared__ float red[4];
  const int lane = tid & 63, wv = tid >> 6;
  if (lane == 0) red[wv] = amax;
  __syncthreads();
  amax = fmaxf(fmaxf(red[0], red[1]), fmaxf(red[2], red[3]));

  const float scale = fmaxf(amax, 1e-7f) * (1.0f / 127.0f);
  const float rs = 1.0f / scale;
  if (tid == 0) scales[row] = scale;

#pragma unroll
  for (int i = 0; i < 4; ++i) {
    float e[4] = {v[i].x, v[i].y, v[i].z, v[i].w};
    unsigned w = 0;
#pragma unroll
    for (int j = 0; j < 4; ++j) {
      float qf = rintf(e[j] * rs);
      qf = fminf(fmaxf(qf, -128.f), 127.f);
      int qi = (int)qf;
      w |= ((unsigned)(qi & 255)) << (8 * j);
    }
    q[(size_t)row * (KDIM / 4) + tid + i * 256] = w;
  }
}

// ---------------------------------------------------------------------------
// Kernel 2: pack int32 weight [N,K] -> int8 [N,K]
// ---------------------------------------------------------------------------
__global__ __launch_bounds__(256) void pack_kernel(
    const int4* __restrict__ w32, unsigned* __restrict__ w8, int n_units)
{
  int idx = blockIdx.x * 256 + threadIdx.x;
  const int stride = gridDim.x * 256;
  for (; idx < n_units; idx += stride) {
    int4 v = w32[idx];
    unsigned d = ((unsigned)(v.x & 255)) | ((unsigned)(v.y & 255) << 8) |
                 ((unsigned)(v.z & 255) << 16) | ((unsigned)(v.w & 255) << 24);
    w8[idx] = d;
  }
}

// ---------------------------------------------------------------------------
// Kernel 3: int8 GEMM, 256x256 tile, 8-phase schedule (faithful m201 port).
// 512 threads = 8 waves (2M x 4N); per-wave output 128x64.
// LDS slots: [2 buf][2 K-half][256 rows][64 B] per operand = 128 KiB.
// Deep prefetch (5-phase flight): during tile t stage kh1(t+1) at ph1/ph2
// and kh0(t+2) at ph3/ph4 (each slot freed by the preceding phase barrier).
// Drains: vmcnt(8) at end-ph2 (publishes kh1(t)) and end-ph4 (kh0(t+1)).
// No sched_barrier(0) anywhere (compiler-visible ds_reads; m141 hazard).
// Swizzle: chunk c ^= ((r>>1)&3), both-sides (verified conflict-free, r6).
// ---------------------------------------------------------------------------
__global__ __launch_bounds__(512, 2) void gemm_i8_kernel(
    const signed char* __restrict__ qa,   // [M,K] int8
    const signed char* __restrict__ wb,   // [N,K] int8
    const float* __restrict__ scales,     // [M]
    const float* __restrict__ wscale,     // [N]
    const float* __restrict__ bias,       // [N]
    float* __restrict__ out)              // [M,N] f32
{
  __shared__ __align__(16) signed char As[2][2][256 * 64];  // 64 KiB
  __shared__ __align__(16) signed char Bs[2][2][256 * 64];  // 64 KiB

  const int tid = threadIdx.x;
  const int lane = tid & 63;
  const int wv = tid >> 6;       // 0..7
  const int wr = wv >> 2;        // 0..1 (M half)
  const int wc = wv & 3;         // 0..3 (N quarter)

  const int n0 = blockIdx.x * BN;
  const int m0 = blockIdx.y * BM;

  const signed char* Ag = qa + (size_t)m0 * KDIM;
  const signed char* Bg = wb + (size_t)n0 * KDIM;

  // stage one 16 KiB half-tile (256 rows x 64 B of K-half kh) for tile kt.
  // LDS dest linear (wave-uniform base + lane*16); swizzle via permuted
  // GLOBAL source chunk: c_g = c_lds ^ ((r>>1)&3).  2 loads per thread.
  auto stageH = [&](signed char* dst, const signed char* g, int kt, int kh) {
#pragma unroll
    for (int i = 0; i < 2; ++i) {
      const int chunk = i * 512 + tid;              // 0..1023
      const int r = chunk >> 2;                     // row 0..255
      const int cg = (chunk & 3) ^ ((r >> 1) & 3);  // swizzled global chunk
      gload_lds16(g + (size_t)r * KDIM + (size_t)kt * BK + kh * 64 + cg * 16,
                  dst + (i * 512 + wv * 64) * 16);
    }
  };

  // fragment reads: global chunk ksel of row r lives at LDS chunk
  // ksel ^ ((r>>1)&3); frag-row bases are multiples of 16 so the XOR term
  // is a per-lane constant.
  const int swz16 = (((lane >> 4) ^ (((lane & 15) >> 1) & 3)) << 4);
  const int frow_a = wr * 128 + (lane & 15);
  const int frow_b = wc * 64 + (lane & 15);

  auto ardA = [&](const signed char* plane, int mi) -> v4i {
    return *(const v4i*)(plane + (frow_a + mi * 16) * 64 + swz16);
  };
  auto ardB = [&](const signed char* plane, int ni) -> v4i {
    return *(const v4i*)(plane + (frow_b + ni * 16) * 64 + swz16);
  };

  v4i acc[8][4] = {};
  v4i bfrag[4];

  // prologue: stage kh0(0), kh1(0), kh0(1)  (12 loads/thread)
  stageH(&As[0][0][0], Ag, 0, 0);
  stageH(&Bs[0][0][0], Bg, 0, 0);
  stageH(&As[0][1][0], Ag, 0, 1);
  stageH(&Bs[0][1][0], Bg, 0, 1);
  stageH(&As[1][0][0], Ag, 1, 0);
  stageH(&Bs[1][0][0], Bg, 1, 0);
  asm volatile("s_waitcnt vmcnt(8)" ::: "memory");  // kh0(0) resident
  __builtin_amdgcn_s_barrier();

  for (int t = 0; t < NT; ++t) {
    const int cur = t & 1;
    const int nxt = cur ^ 1;
    const signed char* A0 = &As[cur][0][0];
    const signed char* A1 = &As[cur][1][0];
    const signed char* B0 = &Bs[cur][0][0];
    const signed char* B1 = &Bs[cur][1][0];
    v4i af[4];

    // ---------- phase 1: kk0, acc rows 0-3 ----------
#pragma unroll
    for (int mi = 0; mi < 4; ++mi) af[mi] = ardA(A0, mi);
#pragma unroll
    for (int ni = 0; ni < 4; ++ni) bfrag[ni] = ardB(B0, ni);
    if (t + 1 < NT) stageH(&As[nxt][1][0], Ag, t + 1, 1);  // slot freed @ t-1 ph4 bar
    __builtin_amdgcn_s_barrier();
    asm volatile("s_waitcnt lgkmcnt(0)" ::: "memory");
    __builtin_amdgcn_s_setprio(1);
#pragma unroll
    for (int mi = 0; mi < 4; ++mi)
#pragma unroll
      for (int ni = 0; ni < 4; ++ni)
        acc[mi][ni] = __builtin_amdgcn_mfma_i32_16x16x64_i8(
            af[mi], bfrag[ni], acc[mi][ni], 0, 0, 0);
    __builtin_amdgcn_s_setprio(0);
    __builtin_amdgcn_s_barrier();

    // ---------- phase 2: kk0, acc rows 4-7 ----------
#pragma unroll
    for (int mi = 0; mi < 4; ++mi) af[mi] = ardA(A0, mi + 4);
    if (t + 1 < NT) stageH(&Bs[nxt][1][0], Bg, t + 1, 1);
    __builtin_amdgcn_s_barrier();
    asm volatile("s_waitcnt lgkmcnt(0)" ::: "memory");
    __builtin_amdgcn_s_setprio(1);
#pragma unroll
    for (int mi = 0; mi < 4; ++mi)
#pragma unroll
      for (int ni = 0; ni < 4; ++ni)
        acc[mi + 4][ni] = __builtin_amdgcn_mfma_i32_16x16x64_i8(
            af[mi], bfrag[ni], acc[mi + 4][ni], 0, 0, 0);
    __builtin_amdgcn_s_setprio(0);
    // publish kh1(t) (staged during tile t-1 ph1/ph2); keep 8 in flight
    if (t + 1 < NT) { asm volatile("s_waitcnt vmcnt(8)" ::: "memory"); }
    else            { asm volatile("s_waitcnt vmcnt(0)" ::: "memory"); }
    __builtin_amdgcn_s_barrier();

    // ---------- phase 3: kk1, acc rows 0-3 ----------
#pragma unroll
    for (int mi = 0; mi < 4; ++mi) af[mi] = ardA(A1, mi);
#pragma unroll
    for (int ni = 0; ni < 4; ++ni) bfrag[ni] = ardB(B1, ni);
    if (t + 2 < NT) stageH(&As[cur][0][0], Ag, t + 2, 0);  // slot freed @ ph2 bar
    __builtin_amdgcn_s_barrier();
    asm volatile("s_waitcnt lgkmcnt(0)" ::: "memory");
    __builtin_amdgcn_s_setprio(1);
#pragma unroll
    for (int mi = 0; mi < 4; ++mi)
#pragma unroll
      for (int ni = 0; ni < 4; ++ni)
        acc[mi][ni] = __builtin_amdgcn_mfma_i32_16x16x64_i8(
            af[mi], bfrag[ni], acc[mi][ni], 0, 0, 0);
    __builtin_amdgcn_s_setprio(0);
    __builtin_amdgcn_s_barrier();

    // ---------- phase 4: kk1, acc rows 4-7 ----------
#pragma unroll
    for (int mi = 0; mi < 4; ++mi) af[mi] = ardA(A1, mi + 4);
    if (t + 2 < NT) stageH(&Bs[cur][0][0], Bg, t + 2, 0);
    __builtin_amdgcn_s_barrier();
    asm volatile("s_waitcnt lgkmcnt(0)" ::: "memory");
    __builtin_amdgcn_s_setprio(1);
#pragma unroll
    for (int mi = 0; mi < 4; ++mi)
#pragma unroll
      for (int ni = 0; ni < 4; ++ni)
        acc[mi + 4][ni] = __builtin_amdgcn_mfma_i32_16x16x64_i8(
            af[mi], bfrag[ni], acc[mi + 4][ni], 0, 0, 0);
    __builtin_amdgcn_s_setprio(0);
    // publish kh0(t+1) (staged during tile t-1 ph3/ph4)
    if (t + 2 < NT)      { asm volatile("s_waitcnt vmcnt(8)" ::: "memory"); }
    else if (t + 1 < NT) { asm volatile("s_waitcnt vmcnt(4)" ::: "memory"); }
    __builtin_amdgcn_s_barrier();
  }

  // epilogue: dequant + bias, f32 store
  const int cl = lane & 15;
  const int rb = (lane >> 4) * 4;
#pragma unroll
  for (int ni = 0; ni < 4; ++ni) {
    const int n = n0 + wc * 64 + ni * 16 + cl;
    const float wsc = wscale[n];
    const float bs = bias[n];
#pragma unroll
    for (int mi = 0; mi < 8; ++mi) {
      const int mb = m0 + wr * 128 + mi * 16 + rb;
#pragma unroll
      for (int j = 0; j < 4; ++j) {
        const int m = mb + j;
        out[(size_t)m * NDIM + n] =
            (float)acc[mi][ni][j] * scales[m] * wsc + bs;
      }
    }
  }
}

// ---------------------------------------------------------------------------
extern "C" void kernel_launch(void* const* d_in, const int* in_sizes, int n_in,
                              void* d_out, int out_size, void* d_ws, size_t ws_size,
                              hipStream_t stream) {
  const float* x = (const float*)d_in[0];        // f32 [M,K] (fp16 upcast)
  const int* w32 = (const int*)d_in[1];          // int32 [N,K]
  const float* wscale = (const float*)d_in[2];   // [N]
  const float* bias = (const float*)d_in[3];     // [N]
  float* out = (float*)d_out;                    // f32 [M,N]

  float* scales = (float*)d_ws;                                  // 16 KB slot
  signed char* qbuf = (signed char*)d_ws + 16384;                // M*K int8
  signed char* wpack = (signed char*)d_ws + 16384 + (size_t)MDIM * KDIM;

  quant_kernel<<<MDIM, 256, 0, stream>>>(x, (unsigned*)qbuf, scales);

  const int n_units = (NDIM * KDIM) / 4;
  pack_kernel<<<2048, 256, 0, stream>>>((const int4*)w32, (unsigned*)wpack,
                                        n_units);

  dim3 grid(NDIM / BN, MDIM / BM);   // 43 x 16
  gemm_i8_kernel<<<grid, 512, 0, stream>>>(qbuf, wpack, scales, wscale, bias,
                                           out);
}